// Round 4
// baseline (352.729 us; speedup 1.0000x reference)
//
#include <hip/hip_runtime.h>

#define EPS_F 0.1f
#define A_F 100.0f
#define NUMNEG_F 10.0f
#define EXP_EPS 1.1051709f   // e^0.1; gate: dist<EPS  <=>  (-inner + s) < e^EPS
#define CAP 64               // per-node capacity; one-sided deg ~ Poisson(10)
#define BATCH 16
#define NBLOCKS 4096
#define FBLOCKS 1024
#define FPER 4               // edges per thread in fill (1024*256*4 >= E)

// ---- K1: fused zero(d_out) + one-sided bucket fill, 4-deep MLP ----
__global__ __launch_bounds__(256) void fill_kernel(
    const int* __restrict__ u_idx, const int* __restrict__ v_idx,
    int* __restrict__ counts, int* __restrict__ entries,
    float* __restrict__ out, int out_n, int E)
{
    const int tid = blockIdx.x * blockDim.x + threadIdx.x;
    const int nth = gridDim.x * blockDim.x;

    // zero d_out (grad accumulated by atomics; energy overwritten by reduce)
    float4* o4 = (float4*)out;
    const int n4 = out_n >> 2;
    for (int i = tid; i < n4; i += nth) o4[i] = float4{0.f, 0.f, 0.f, 0.f};
    if (tid == 0)
        for (int i = n4 * 4; i < out_n; i++) out[i] = 0.f;

    // phase-split bucket fill: 4 loads -> 4 independent atomics -> 4 stores
    int us[FPER], vv[FPER], sl[FPER];
    #pragma unroll
    for (int j = 0; j < FPER; j++) {
        const int i = tid + j * nth;
        us[j] = (i < E) ? u_idx[i] : -1;
        vv[j] = (i < E) ? v_idx[i] : 0;
    }
    #pragma unroll
    for (int j = 0; j < FPER; j++)
        sl[j] = (us[j] >= 0) ? atomicAdd(&counts[us[j]], 1) : CAP;
    #pragma unroll
    for (int j = 0; j < FPER; j++)
        if (us[j] >= 0 && sl[j] < CAP)
            entries[(size_t)us[j] * CAP + sl[j]] = vv[j];

    // safety net for E > nth*FPER (not hit at E=1M)
    for (int i = tid + FPER * nth; i < E; i += nth) {
        const int u = u_idx[i];
        const int s = atomicAdd(&counts[u], 1);
        if (s < CAP) entries[(size_t)u * CAP + s] = v_idx[i];
    }
}

// fold-merge: reduce two edges' partial-product vectors one level.
__device__ __forceinline__ float red2(float a, float b, int dist, bool sel) {
    const float fa = a + __shfl_xor(a, dist, 64);
    const float fb = b + __shfl_xor(b, dist, 64);
    return sel ? fb : fa;
}

// ---- K2: one wave per node u (each edge once), 2-node software pipeline:
//      node X+1's xv gathers issue before node X's reduce/epilogue/scatter.
//      Transpose-reduce puts edge e's inner in lane group e; epilogue is
//      lane-parallel. grad_u in registers; grad_v 256B atomic rows. ----
__global__ __launch_bounds__(256) void node_kernel(
    const float* __restrict__ x,
    const int* __restrict__ counts,
    const int* __restrict__ entries,
    float* __restrict__ out,          // out[0]=energy, out+1 = grad
    float* __restrict__ block_energy,
    int N)
{
    const int lane = threadIdx.x & 63;
    const int wib  = threadIdx.x >> 6;
    const int wave = (blockIdx.x * blockDim.x + threadIdx.x) >> 6;
    const int nwaves = (gridDim.x * blockDim.x) >> 6;
    const float sign = (lane == 0) ? -1.0f : 1.0f;   // Minkowski J
    float* __restrict__ grad = out + 1;

    const bool m32 = (lane & 32) != 0;
    const bool m16 = (lane & 16) != 0;
    const bool m8  = (lane & 8)  != 0;
    const bool m4  = (lane & 4)  != 0;
    const int  e4  = lane >> 2;

    float eacc = 0.0f;

    // issue xu + first-batch xv gathers for a node (myv must have arrived)
    auto gather_batch = [&](int u, int deg, int myv, float& xuj,
                            int (&vs)[BATCH], float (&xv)[BATCH]) -> int {
        xuj = x[(size_t)u * 64 + lane] * sign;
        const int bn = min(deg, BATCH);
        #pragma unroll
        for (int k = 0; k < BATCH; k++) {
            if (k < bn) {
                vs[k] = __builtin_amdgcn_readlane(myv, k);
                xv[k] = x[(size_t)vs[k] * 64 + lane];
            } else { vs[k] = 0; xv[k] = 0.0f; }
        }
        return bn;
    };

    // reduce + epilogue + scatter for one 16-edge batch
    auto process_batch = [&](float xuj, int (&vs)[BATCH], float (&xv)[BATCH],
                             int bn, float& gacc) {
        float p[BATCH];
        #pragma unroll
        for (int k = 0; k < BATCH; k++) p[k] = xuj * xv[k];

        float q0 = red2(p[0], p[8],  32, m32);
        float q1 = red2(p[1], p[9],  32, m32);
        float q2 = red2(p[2], p[10], 32, m32);
        float q3 = red2(p[3], p[11], 32, m32);
        float q4 = red2(p[4], p[12], 32, m32);
        float q5 = red2(p[5], p[13], 32, m32);
        float q6 = red2(p[6], p[14], 32, m32);
        float q7 = red2(p[7], p[15], 32, m32);
        float r0 = red2(q0, q4, 16, m16);
        float r1 = red2(q1, q5, 16, m16);
        float r2 = red2(q2, q6, 16, m16);
        float r3 = red2(q3, q7, 16, m16);
        float s0 = red2(r0, r2, 8, m8);
        float s1 = red2(r1, r3, 8, m8);
        float t0 = red2(s0, s1, 4, m4);
        t0 += __shfl_xor(t0, 2, 64);
        t0 += __shfl_xor(t0, 1, 64);

        const float inner = fminf(t0, -1.0f - 1e-7f);
        const float s     = __builtin_amdgcn_sqrtf(fmaf(inner, inner, -1.0f));
        const float t     = s - inner;                  // dist = log(t)
        const bool  act   = (t < EXP_EPS) & (e4 < bn);
        const float dist  = __logf(t);
        const float delta = act ? (EPS_F - dist) : 0.0f;
        eacc = fmaf(delta, delta, eacc);
        const float factor = (-(A_F / NUMNEG_F)) * delta *
                             __builtin_amdgcn_rcpf(s + 1e-9f);

        const unsigned long long ball = __ballot(act);
        #pragma unroll
        for (int k = 0; k < BATCH; k++) {
            if ((ball >> (4 * k)) & 1ull) {
                const float fk = __uint_as_float(
                    __builtin_amdgcn_readlane(__float_as_uint(factor), 4 * k));
                unsafeAtomicAdd(&grad[(size_t)vs[k] * 64 + lane], fk * xuj);
                gacc = fmaf(fk, xv[k], gacc);
            }
        }
    };

    // full node: pre-gathered first batch + synchronous overflow batches
    auto compute_node = [&](int u, int deg, int myv, float xuj,
                            int (&vs)[BATCH], float (&xv)[BATCH], int bn) {
        float gacc = 0.0f;
        process_batch(xuj, vs, xv, bn, gacc);
        const int deg_c = min(deg, CAP);
        for (int k0 = BATCH; k0 < deg_c; k0 += BATCH) {  // ~2.6% of nodes
            const int bn2 = min(BATCH, deg_c - k0);
            int vs2[BATCH]; float xv2[BATCH];
            #pragma unroll
            for (int k = 0; k < BATCH; k++) {
                if (k < bn2) {
                    vs2[k] = __builtin_amdgcn_readlane(myv, k0 + k);
                    xv2[k] = x[(size_t)vs2[k] * 64 + lane];
                } else { vs2[k] = 0; xv2[k] = 0.0f; }
            }
            process_batch(xuj, vs2, xv2, bn2, gacc);
        }
        if (deg_c > 0)
            unsafeAtomicAdd(&grad[(size_t)u * 64 + lane], gacc * sign);
    };

    // ---- 2-node pipeline: banks A (even slots) and B (odd slots) ----
    int uA = wave, uB = wave + nwaves;
    int degA = 0, myvA = 0, degB = 0, myvB = 0;
    if (uA < N) { degA = counts[uA]; myvA = entries[(size_t)uA * CAP + lane]; }
    if (uB < N) { degB = counts[uB]; myvB = entries[(size_t)uB * CAP + lane]; }

    float xuA = 0.0f, xuB = 0.0f;
    int vsA[BATCH], vsB[BATCH];
    float xvA[BATCH], xvB[BATCH];
    int bnA = 0, bnB = 0;

    if (uA < N) bnA = gather_batch(uA, degA, myvA, xuA, vsA, xvA);

    while (uA < N) {
        // issue B's gathers (overlap with A's compute)
        if (uB < N) bnB = gather_batch(uB, degB, myvB, xuB, vsB, xvB);
        // prefetch adjacency two slots ahead for A
        const int uA2 = uA + 2 * nwaves;
        int degA2 = 0, myvA2 = 0;
        if (uA2 < N) { degA2 = counts[uA2]; myvA2 = entries[(size_t)uA2 * CAP + lane]; }
        // compute A
        compute_node(uA, degA, myvA, xuA, vsA, xvA, bnA);
        uA = uA2; degA = degA2; myvA = myvA2;

        if (uB >= N) break;
        // issue A's (new) gathers (overlap with B's compute)
        if (uA < N) bnA = gather_batch(uA, degA, myvA, xuA, vsA, xvA);
        // prefetch adjacency two slots ahead for B
        const int uB2 = uB + 2 * nwaves;
        int degB2 = 0, myvB2 = 0;
        if (uB2 < N) { degB2 = counts[uB2]; myvB2 = entries[(size_t)uB2 * CAP + lane]; }
        // compute B
        compute_node(uB, degB, myvB, xuB, vsB, xvB, bnB);
        uB = uB2; degB = degB2; myvB = myvB2;
    }

    // wave-reduce energy (each edge counted on 4 lanes -> *0.25)
    #pragma unroll
    for (int off = 32; off >= 1; off >>= 1) eacc += __shfl_xor(eacc, off, 64);
    __shared__ float se[4];
    if (lane == 0) se[wib] = eacc * 0.25f;
    __syncthreads();
    if (threadIdx.x == 0)
        block_energy[blockIdx.x] = se[0] + se[1] + se[2] + se[3];
}

// ---- K3: final energy reduce ----
__global__ __launch_bounds__(256) void energy_reduce_kernel(
    const float* __restrict__ block_energy, float* __restrict__ out, int n)
{
    const int lane = threadIdx.x & 63;
    const int wib  = threadIdx.x >> 6;
    float s = 0.0f;
    for (int i = threadIdx.x; i < n; i += 256) s += block_energy[i];
    #pragma unroll
    for (int off = 32; off >= 1; off >>= 1) s += __shfl_xor(s, off, 64);
    __shared__ float se[4];
    if (lane == 0) se[wib] = s;
    __syncthreads();
    if (threadIdx.x == 0)
        out[0] = (se[0] + se[1] + se[2] + se[3]) * (0.5f * A_F / NUMNEG_F);
}

extern "C" void kernel_launch(void* const* d_in, const int* in_sizes, int n_in,
                              void* d_out, int out_size, void* d_ws, size_t ws_size,
                              hipStream_t stream) {
    const float* x     = (const float*)d_in[0];
    const int*   u_idx = (const int*)d_in[1];
    const int*   v_idx = (const int*)d_in[2];
    float* out = (float*)d_out;
    const int E = in_sizes[1];
    const int N = in_sizes[0] / 64;

    // ws layout
    char* ws = (char*)d_ws;
    int*   counts       = (int*)ws;                          // N ints
    int*   entries      = (int*)(ws + (1 << 20));            // N*CAP ints (~25.6 MB)
    float* block_energy = (float*)(ws + (1 << 20) + (size_t)N * CAP * 4 + (1 << 20));

    // counts must start at zero (400 KB — cheap)
    hipMemsetAsync(counts, 0, (size_t)N * sizeof(int), stream);

    // fused: zero d_out + one-sided bucket fill (4-deep MLP)
    fill_kernel<<<FBLOCKS, 256, 0, stream>>>(u_idx, v_idx, counts, entries,
                                             out, out_size, E);

    node_kernel<<<NBLOCKS, 256, 0, stream>>>(x, counts, entries, out, block_energy, N);

    energy_reduce_kernel<<<1, 256, 0, stream>>>(block_energy, out, NBLOCKS);
}